// Round 18
// baseline (125.978 us; speedup 1.0000x reference)
//
#include <hip/hip_runtime.h>
#include <hip/hip_bf16.h>

// Problem constants
#define L_ACT   12
#define BDIM    16
#define PDIM    128
#define DSUM    128
#define HID     512
#define ODIM    2048
#define NHEAD   16
#define DHEAD   64
#define MROWS   2048   // B*P rows per layer

typedef short s16x4  __attribute__((ext_vector_type(4)));
typedef short short8 __attribute__((ext_vector_type(8)));
typedef float f32x4  __attribute__((ext_vector_type(4)));

__device__ __forceinline__ void gload_lds16(const __hip_bfloat16* g, __hip_bfloat16* l) {
  __builtin_amdgcn_global_load_lds(
      (const __attribute__((address_space(1))) unsigned int*)g,
      (__attribute__((address_space(3))) unsigned int*)l, 16, 0, 0);
}

__device__ __forceinline__ short f2bf(float x) {
  __hip_bfloat16 h = __float2bfloat16(x);
  return *reinterpret_cast<short*>(&h);
}

// LDS-only barrier: orders LDS state without draining vmcnt, letting
// global stores / prefetch loads pipeline across barriers.
#define LBAR() do {                                                   \
    asm volatile("s_waitcnt lgkmcnt(0)" ::: "memory");                \
    __builtin_amdgcn_s_barrier();                                     \
  } while (0)

// --- zero-fill (fallback path only) ---
__global__ __launch_bounds__(256) void zerofill_kernel(f32x4* __restrict__ p, int n16) {
  int stride = gridDim.x * 256;
  for (int i = blockIdx.x * 256 + threadIdx.x; i < n16; i += stride)
    p[i] = {0.f, 0.f, 0.f, 0.f};
}

// --- GEMM1 (R17-proven, unchanged): 128x128 tile, 4 waves, bias+relu, bf16
//     out. A staged per-kt from f32 summary; B staged once per block from
//     f32 W1; block 0 computes cos/sin; H via LDS transpose; fused pipelined
//     64x64 W2 -> W2T transpose; LDS-only barriers; zero-fill spread. ---
__global__ __launch_bounds__(256) void gemm1_128(
    const float* __restrict__ summary,          // [2048][128] f32
    const float* __restrict__ W1,               // [12][128][512] f32
    const int*   __restrict__ positions,
    const float* __restrict__ bias,
    __hip_bfloat16* __restrict__ Hall,
    const float* __restrict__ W2,
    __hip_bfloat16* __restrict__ W2T,
    float* __restrict__ cs,
    f32x4* __restrict__ zeroBase, int doZero) {
  const int KTOT = DSUM, NTOT = HID;
  __shared__ __hip_bfloat16 shbuf[24576];   // 49152B: B2 32KB | A 16KB (tail reuses)
  __hip_bfloat16* ldsB2 = shbuf;            // [128 r][256B] full-K swizzled B tile
  __hip_bfloat16* ldsA  = shbuf + 16384;    // per-kt A tile [128 r][128B]
  const int l    = blockIdx.z;
  const int n0   = blockIdx.x * 128;
  const int m0   = blockIdx.y * 128;
  const int tid  = threadIdx.x;
  const int wid  = tid >> 6;
  const int lane = tid & 63;
  const int wr = wid >> 1, wc = wid & 1;
  const int bid = blockIdx.x + 4 * blockIdx.y + 64 * blockIdx.z;   // 0..767

  const f32x4 z = {0.f, 0.f, 0.f, 0.f};
  f32x4* zp = zeroBase + (size_t)bid * 8192;   // 128KB chunk, slot groups 0..31

  // block 0: cos/sin table (consumed by gemm2; stream order guarantees visibility)
  if (bid == 0) {
#pragma unroll
    for (int q = 0; q < 4; ++q) {
      int i = q * 256 + tid;
      int p = i >> 3, f = i & 7;
      double inv = pow(10000.0, -(double)f / 8.0);
      double ang = (double)positions[p] * inv;
      cs[i]        = (float)cos(ang);
      cs[1024 + i] = (float)sin(ang);
    }
  }

  // W2-tail geometry: 4 tiles/block of 64j x 64o
  const int rowg = tid >> 4;          // 0..15
  const int colg = tid & 15;          // o granule (4 f32)
  const int orow = tid >> 3;          // 0..31
  const int jg   = tid & 7;           // j granule (8 bf16)
  const int tbase4 = bid * 4;
  f32x4 rvA0, rvA1, rvA2, rvA3, rvB0, rvB1, rvB2, rvB3;

#define W2_LOAD(P, tt_) do {                                                \
      int t_ = tbase4 + (tt_);                                              \
      int lz_ = t_ >> 8, rem_ = t_ & 255;                                   \
      int j0_ = (rem_ >> 5) * 64, o0_ = (rem_ & 31) * 64;                   \
      const float* ip_ = W2 + (size_t)lz_ * HID * ODIM                      \
                       + (size_t)(j0_ + rowg) * ODIM + o0_ + colg * 4;      \
      P##0 = *(const f32x4*)(ip_);                                          \
      P##1 = *(const f32x4*)(ip_ + (size_t)16 * ODIM);                      \
      P##2 = *(const f32x4*)(ip_ + (size_t)32 * ODIM);                      \
      P##3 = *(const f32x4*)(ip_ + (size_t)48 * ODIM);                      \
    } while (0)

  // B2 staging: W1[l][j][n0+r] -> ldsB2[r][(j4>>1)^(r&7)][j4&1]
  {
    const float* Wp = W1 + (size_t)l * DSUM * HID + n0;
#pragma unroll
    for (int q = 0; q < 16; ++q) {
      int g  = q * 256 + tid;
      int j4 = g >> 7;            // 0..31 (4 consecutive j)
      int r  = g & 127;
      s16x4 w;
#pragma unroll
      for (int jj = 0; jj < 4; ++jj)
        w[jj] = f2bf(Wp[(size_t)(j4 * 4 + jj) * HID + r]);
      int chunk = (j4 >> 1) ^ (r & 7);
      *(s16x4*)((char*)ldsB2 + r * 256 + chunk * 16 + (j4 & 1) * 8) = w;
    }
  }

  // pre-issue W2-tail tiles 0,1: HBM latency hides under K-loop + H epilogue
  W2_LOAD(rvA, 0);
  W2_LOAD(rvB, 1);

  f32x4 acc[4][4];
#pragma unroll
  for (int m = 0; m < 4; ++m)
#pragma unroll
    for (int n = 0; n < 4; ++n)
      acc[m][n] = {0.f, 0.f, 0.f, 0.f};

  const int kq = lane >> 4;

  for (int kt = 0; kt < KTOT / 64; ++kt) {
    LBAR();   // kt=0: orders B2 writes before reads; also guards ldsA reuse
    if (doZero) {
#pragma unroll
      for (int q = 0; q < 4; ++q)
        __builtin_nontemporal_store(z, zp + (kt * 4 + q) * 256 + tid);
    }
    // A: reg-staged f32 -> bf16, swizzled ds_write_b64
#pragma unroll
    for (int j = 0; j < 8; ++j) {
      int s = j * 256 + tid;
      int r = s >> 4, g = s & 15;
      f32x4 v = *(const f32x4*)(summary + (size_t)(m0 + r) * DSUM + kt * 64 + g * 4);
      s16x4 w;
      w[0] = f2bf(v[0]); w[1] = f2bf(v[1]); w[2] = f2bf(v[2]); w[3] = f2bf(v[3]);
      int ch = g >> 1;
      *(s16x4*)((char*)ldsA + r * 128 + ((ch ^ (r & 7)) << 4) + (g & 1) * 8) = w;
    }
    LBAR();
#pragma unroll
    for (int kk = 0; kk < 2; ++kk) {
      short8 af[4], bfr[4];
#pragma unroll
      for (int m = 0; m < 4; ++m) {
        int row = wr * 64 + m * 16 + (lane & 15);
        int off = (kk * 64 + kq * 16) ^ ((row & 7) << 4);
        af[m] = *(const short8*)((const char*)ldsA + row * 128 + off);
      }
#pragma unroll
      for (int n = 0; n < 4; ++n) {
        int row = wc * 64 + n * 16 + (lane & 15);
        int chunk = (kt * 8 + kk * 4 + kq) ^ (row & 7);
        bfr[n] = *(const short8*)((const char*)ldsB2 + row * 256 + chunk * 16);
      }
#pragma unroll
      for (int m = 0; m < 4; ++m)
#pragma unroll
        for (int n = 0; n < 4; ++n)
          acc[m][n] = __builtin_amdgcn_mfma_f32_16x16x32_bf16(af[m], bfr[n], acc[m][n], 0, 0, 0);
    }
  }

  // H epilogue via LDS: [128][136] bf16 padded tile -> 256B-run stores
  LBAR();
#pragma unroll
  for (int n = 0; n < 4; ++n) {
    int col = wc * 64 + n * 16 + (lane & 15);
    float bb = bias[l * NTOT + n0 + col];
#pragma unroll
    for (int m = 0; m < 4; ++m) {
      int rowb = wr * 64 + m * 16 + ((lane >> 4) << 2);
#pragma unroll
      for (int j = 0; j < 4; ++j) {
        float v = acc[m][n][j] + bb;
        v = v > 0.f ? v : 0.f;
        shbuf[(rowb + j) * 136 + col] = __float2bfloat16(v);
      }
    }
  }
  if (doZero) {
#pragma unroll
    for (int i = 0; i < 8; ++i)
      __builtin_nontemporal_store(z, zp + (8 + i) * 256 + tid);
  }
  LBAR();
  {
    __hip_bfloat16* H = Hall + (size_t)l * MROWS * HID;
#pragma unroll
    for (int i = 0; i < 8; ++i) {
      int idx = i * 256 + tid;
      int row = idx >> 4, seg = idx & 15;
      short8 v = *(const short8*)(shbuf + row * 136 + seg * 8);
      *(short8*)(H + (size_t)(m0 + row) * HID + n0 + seg * 8) = v;
    }
  }
  LBAR();   // H LDS reads done before W2 section overwrites shbuf

  // fused W2 -> W2T transpose: 4 x (64j x 64o) tiles, dbuf [64][68] f32 with
  // granule-XOR swizzle, 2-deep reg prefetch, interleaved nt zero-fill.
  {
    float* tb0 = (float*)shbuf;            // 64x68 f32 = 17408B
    float* tb1 = (float*)shbuf + 4352;

#define W2_WRITE(buf, P) do {                                               \
      _Pragma("unroll")                                                     \
      for (int p_ = 0; p_ < 4; ++p_) {                                      \
        int j_ = rowg + 16 * p_;                                            \
        f32x4 vv_ = (p_ == 0) ? P##0 : (p_ == 1) ? P##1 : (p_ == 2) ? P##2 : P##3; \
        *(f32x4*)&(buf)[j_ * 68 + 4 * (colg ^ (j_ >> 3))] = vv_;            \
      }                                                                     \
    } while (0)

#define W2_STORE(buf, tt_) do {                                             \
      int t_ = tbase4 + (tt_);                                              \
      int lz_ = t_ >> 8, rem_ = t_ & 255;                                   \
      int j0_ = (rem_ >> 5) * 64, o0_ = (rem_ & 31) * 64;                   \
      __hip_bfloat16* op_ = W2T + (size_t)lz_ * HID * ODIM;                 \
      _Pragma("unroll")                                                     \
      for (int p_ = 0; p_ < 2; ++p_) {                                      \
        int or_ = orow + 32 * p_;                                           \
        short8 w_;                                                          \
        _Pragma("unroll")                                                   \
        for (int i_ = 0; i_ < 8; ++i_)                                      \
          w_[i_] = f2bf((buf)[(jg * 8 + i_) * 68 + (or_ ^ (4 * jg))]);      \
        *(short8*)(op_ + (size_t)(o0_ + or_) * HID + j0_ + jg * 8) = w_;    \
      }                                                                     \
    } while (0)

#define ZCHUNK(tt_) do { if (doZero) {                                      \
      _Pragma("unroll")                                                     \
      for (int q_ = 0; q_ < 4; ++q_)                                        \
        __builtin_nontemporal_store(z, zp + (16 + (tt_) * 4 + q_) * 256 + tid); \
    } } while (0)

    W2_WRITE(tb0, rvA);
    LBAR();
#pragma unroll 1
    for (int tt = 0; tt < 4; tt += 2) {
      if (tt + 2 < 4) W2_LOAD(rvA, tt + 2);
      W2_STORE(tb0, tt);
      W2_WRITE(tb1, rvB);
      ZCHUNK(tt);
      LBAR();
      if (tt + 3 < 4) W2_LOAD(rvB, tt + 3);
      W2_STORE(tb1, tt + 1);
      if (tt + 2 < 4) W2_WRITE(tb0, rvA);
      ZCHUNK(tt + 1);
      LBAR();
    }
#undef W2_LOAD
#undef W2_WRITE
#undef W2_STORE
#undef ZCHUNK
  }
}

// --- GEMM2: R12 K-loop with PURE-LOAD vmcnt ladder (zero stores moved to
//     the epilogue: the old in-loop store made vmcnt(6) retire the store
//     issued that same iteration -> per-K-step HBM-commit stall). Epilogue
//     barrier is LDS-only. Everything else identical. ---
__global__ __launch_bounds__(256, 2) void gemm2_pipe(
    const __hip_bfloat16* __restrict__ Aall,   // h_bf [12][2048][512]
    const __hip_bfloat16* __restrict__ Ball,   // W2T  [12][2048][512]
    const float* __restrict__ bias,            // b2   [12][2048]
    const float* __restrict__ cs,
    float* __restrict__ O,
    f32x4* __restrict__ zeroBase, int doZero) {
  __shared__ __hip_bfloat16 lds[3 * 12288];    // 3 slots x (A 16KB + B 8KB) = 72 KiB
  const int orig = blockIdx.x + 16 * blockIdx.y + 128 * blockIdx.z;   // x fastest
  const int nw   = (orig & 7) * 192 + (orig >> 3);   // bijective, 1536 % 8 == 0
  const int bx   = nw & 15;
  const int by   = (nw >> 4) & 7;
  const int l    = nw >> 7;
  const int n0  = bx * 128;
  const int m0  = by * 256;
  const int tid = threadIdx.x;
  const int wid = tid >> 6, lane = tid & 63;
  const int wm  = wid >> 1, wn = wid & 1;
  const __hip_bfloat16* A  = Aall + (size_t)l * MROWS * HID;
  const __hip_bfloat16* Bt = Ball + (size_t)l * ODIM * HID;
  f32x4* zq = zeroBase + (size_t)nw * 4096;    // 64KB slice of [0, 96MB)
  const f32x4 zv = {0.f, 0.f, 0.f, 0.f};

  f32x4 acc[8][4];
#pragma unroll
  for (int m = 0; m < 8; ++m)
#pragma unroll
    for (int n = 0; n < 4; ++n)
      acc[m][n] = {0.f, 0.f, 0.f, 0.f};

  int ra[4], ca[4], rb[2], cb[2];
#pragma unroll
  for (int j = 0; j < 4; ++j) {
    int cx = j * 256 + tid;
    ra[j] = cx >> 2; ca[j] = (cx & 3) ^ ((ra[j] >> 1) & 3);
  }
#pragma unroll
  for (int j = 0; j < 2; ++j) {
    int cx = j * 256 + tid;
    rb[j] = cx >> 2; cb[j] = (cx & 3) ^ ((rb[j] >> 1) & 3);
  }

#define STAGE_A(slot, kt) do {                                                      \
    _Pragma("unroll")                                                               \
    for (int j_ = 0; j_ < 4; ++j_)                                                  \
      gload_lds16(A + (size_t)(m0 + ra[j_]) * HID + (kt) * 32 + ca[j_] * 8,         \
                  lds + (slot) * 12288 + j_ * 2048 + wid * 512);                    \
  } while (0)
#define STAGE_B(slot, kt) do {                                                      \
    _Pragma("unroll")                                                               \
    for (int j_ = 0; j_ < 2; ++j_)                                                  \
      gload_lds16(Bt + (size_t)(n0 + rb[j_]) * HID + (kt) * 32 + cb[j_] * 8,        \
                  lds + (slot) * 12288 + 8192 + j_ * 2048 + wid * 512);             \
  } while (0)

  const int kq   = lane >> 4;
  const int rl15 = lane & 15;

#define LD_FRAG(dst, base, rr) do {                                                 \
    int r_ = (rr);                                                                  \
    int off_ = r_ * 64 + ((kq ^ ((r_ >> 1) & 3)) << 4);                             \
    dst = *(const short8*)((const char*)(base) + off_);                             \
  } while (0)

  // prologue: 2 tiles in flight (6 loads/thread per tile)
  STAGE_A(0, 0); STAGE_B(0, 0);
  STAGE_A(1, 1); STAGE_B(1, 1);
  asm volatile("s_waitcnt vmcnt(6)" ::: "memory");   // tile 0 landed
  __builtin_amdgcn_s_barrier();

  const int NT = HID / 32;   // 16
  for (int t = 0; t < NT; ++t) {
    const int cur = t % 3;
    const __hip_bfloat16* sa = lds + cur * 12288;
    const __hip_bfloat16* sb = sa + 8192;
    short8 af[4], bfr[4];

    // ---- phase 0: m-frags 0..3 ----
#pragma unroll
    for (int n = 0; n < 4; ++n) LD_FRAG(bfr[n], sb, wn * 64 + n * 16 + rl15);
#pragma unroll
    for (int mi = 0; mi < 4; ++mi) LD_FRAG(af[mi], sa, wm * 128 + mi * 16 + rl15);
    if (t + 2 < NT) STAGE_A((t + 2) % 3, t + 2);
    __builtin_amdgcn_s_barrier();
    __builtin_amdgcn_s_setprio(1);
#pragma unroll
    for (int mi = 0; mi < 4; ++mi)
#pragma unroll
      for (int n = 0; n < 4; ++n)
        acc[mi][n] = __builtin_amdgcn_mfma_f32_16x16x32_bf16(af[mi], bfr[n], acc[mi][n], 0, 0, 0);
    __builtin_amdgcn_s_setprio(0);
    __builtin_amdgcn_s_barrier();

    // ---- phase 1: m-frags 4..7 (bfr reused) ----
#pragma unroll
    for (int mi = 0; mi < 4; ++mi) LD_FRAG(af[mi], sa, wm * 128 + 64 + mi * 16 + rl15);
    if (t + 2 < NT) STAGE_B((t + 2) % 3, t + 2);
    __builtin_amdgcn_s_barrier();
    __builtin_amdgcn_s_setprio(1);
#pragma unroll
    for (int mi = 0; mi < 4; ++mi)
#pragma unroll
      for (int n = 0; n < 4; ++n)
        acc[4 + mi][n] = __builtin_amdgcn_mfma_f32_16x16x32_bf16(af[mi], bfr[n], acc[4 + mi][n], 0, 0, 0);
    __builtin_amdgcn_s_setprio(0);
    if (t < NT - 2)       asm volatile("s_waitcnt vmcnt(6)" ::: "memory");
    else if (t == NT - 2) asm volatile("s_waitcnt vmcnt(0)" ::: "memory");
    __builtin_amdgcn_s_barrier();
  }
#undef STAGE_A
#undef STAGE_B
#undef LD_FRAG

  // ---- epilogue: bias + RoPE in-reg, per-wave LDS transpose, nt 1KB stores,
  //      zero-fill interleaved (moved out of the K-loop) ----
  LBAR();   // LDS-only: K-loop tiles -> Tw reuse (nothing outstanding in vmcnt)
  const int head = bx;
  const int tkv  = wn;
  const int bidx = by * 2 + wm;
  float* slab = O + ((((size_t)(l + L_ACT) * 2 + tkv) * BDIM + bidx) * NHEAD + head) * (PDIM * DHEAD);
  const bool ropeWave = (tkv == 0);

  float bb[4];
#pragma unroll
  for (int n = 0; n < 4; ++n) bb[n] = bias[l * ODIM + n0 + wn * 64 + n * 16 + rl15];

  float* Tw = (float*)lds + wid * 2080;   // 32 x 65 f32 per wave

#pragma unroll
  for (int c = 0; c < 4; ++c) {           // p-chunk [c*32, c*32+32)
    if (doZero) {
#pragma unroll
      for (int q = 0; q < 4; ++q)
        __builtin_nontemporal_store(zv, zq + (c * 4 + q) * 256 + tid);
    }
#pragma unroll
    for (int mh = 0; mh < 2; ++mh) {
      int mf = c * 2 + mh;
      int pl = mh * 16 + (lane >> 4) * 4;
#pragma unroll
      for (int n = 0; n < 4; ++n) {
#pragma unroll
        for (int j = 0; j < 4; ++j) {
          float v = acc[mf][n][j] + bb[n];
          if (ropeWave && n == 0) {
            float partner = __shfl_xor(v, 8);
            int p = c * 32 + pl + j;
            float cv = cs[p * 8 + (lane & 7)];
            float sv = cs[1024 + p * 8 + (lane & 7)];
            v = v * cv + (((lane & 15) < 8) ? -partner : partner) * sv;
          }
          Tw[(pl + j) * 65 + n * 16 + rl15] = v;
        }
      }
    }
#pragma unroll
    for (int it = 0; it < 8; ++it) {
      int pl = it * 4 + (lane >> 4);
      f32x4 vv = *(const f32x4*)(Tw + pl * 65 + rl15 * 4);
      __builtin_nontemporal_store(vv, (f32x4*)(slab + (size_t)(c * 32 + pl) * DHEAD + rl15 * 4));
    }
  }
}

extern "C" void kernel_launch(void* const* d_in, const int* in_sizes, int n_in,
                              void* d_out, int out_size, void* d_ws, size_t ws_size,
                              hipStream_t stream) {
  const float* summary   = (const float*)d_in[0];
  const int*   positions = (const int*)d_in[1];
  const float* W1 = (const float*)d_in[2];
  const float* b1 = (const float*)d_in[3];
  const float* W2 = (const float*)d_in[4];
  const float* b2 = (const float*)d_in[5];
  float* out = (float*)d_out;

  // Scratch: h_bf 25165824 | W2T 25165824 | cs 8192
  const size_t SCRATCH_BYTES = 25165824ULL + 25165824ULL + 8192ULL;
  const bool useWs = (ws_size >= SCRATCH_BYTES);
  char* sc = useWs ? (char*)d_ws : (char*)d_out;
  __hip_bfloat16* h_bf = (__hip_bfloat16*)sc;
  __hip_bfloat16* W2T  = (__hip_bfloat16*)(sc + 25165824);
  float*          cs   = (float*)(sc + 50331648);

  // zero region split: gemm2 covers [0, 100663296), gemm1 covers the rest.
  gemm1_128<<<dim3(HID / 128, MROWS / 128, L_ACT), 256, 0, stream>>>(
      summary, W1, positions, b1, h_bf, W2, W2T, cs,
      (f32x4*)((char*)d_out + 100663296), useWs ? 1 : 0);
  gemm2_pipe<<<dim3(ODIM / 128, MROWS / 256, L_ACT), 256, 0, stream>>>(
      h_bf, W2T, b2, cs, out, (f32x4*)d_out, useWs ? 1 : 0);

  if (!useWs)   // scratch aliased d_out: zero AFTER gemm2 has consumed it
    zerofill_kernel<<<2048, 256, 0, stream>>>((f32x4*)d_out, 12582912);
}

// Round 19
// 116.710 us; speedup vs baseline: 1.0794x; 1.0794x over previous
//
#include <hip/hip_runtime.h>
#include <hip/hip_bf16.h>

// Problem constants
#define L_ACT   12
#define BDIM    16
#define PDIM    128
#define DSUM    128
#define HID     512
#define ODIM    2048
#define NHEAD   16
#define DHEAD   64
#define MROWS   2048   // B*P rows per layer

typedef short s16x4  __attribute__((ext_vector_type(4)));
typedef short short8 __attribute__((ext_vector_type(8)));
typedef float f32x4  __attribute__((ext_vector_type(4)));

__device__ __forceinline__ void gload_lds16(const __hip_bfloat16* g, __hip_bfloat16* l) {
  __builtin_amdgcn_global_load_lds(
      (const __attribute__((address_space(1))) unsigned int*)g,
      (__attribute__((address_space(3))) unsigned int*)l, 16, 0, 0);
}

__device__ __forceinline__ short f2bf(float x) {
  __hip_bfloat16 h = __float2bfloat16(x);
  return *reinterpret_cast<short*>(&h);
}

// LDS-only barrier: orders LDS state without draining vmcnt, letting
// global stores / prefetch loads pipeline across barriers.
#define LBAR() do {                                                   \
    asm volatile("s_waitcnt lgkmcnt(0)" ::: "memory");                \
    __builtin_amdgcn_s_barrier();                                     \
  } while (0)

// --- zero-fill (fallback path only) ---
__global__ __launch_bounds__(256) void zerofill_kernel(f32x4* __restrict__ p, int n16) {
  int stride = gridDim.x * 256;
  for (int i = blockIdx.x * 256 + threadIdx.x; i < n16; i += stride)
    p[i] = {0.f, 0.f, 0.f, 0.f};
}

// --- GEMM1 (R17-proven, unchanged): 128x128 tile, 4 waves, bias+relu, bf16
//     out. A staged per-kt from f32 summary; B staged once per block from
//     f32 W1; block 0 computes cos/sin; H via LDS transpose; fused pipelined
//     64x64 W2 -> W2T transpose; LDS-only barriers; zero-fill spread. ---
__global__ __launch_bounds__(256) void gemm1_128(
    const float* __restrict__ summary,          // [2048][128] f32
    const float* __restrict__ W1,               // [12][128][512] f32
    const int*   __restrict__ positions,
    const float* __restrict__ bias,
    __hip_bfloat16* __restrict__ Hall,
    const float* __restrict__ W2,
    __hip_bfloat16* __restrict__ W2T,
    float* __restrict__ cs,
    f32x4* __restrict__ zeroBase, int doZero) {
  const int KTOT = DSUM, NTOT = HID;
  __shared__ __hip_bfloat16 shbuf[24576];   // 49152B: B2 32KB | A 16KB (tail reuses)
  __hip_bfloat16* ldsB2 = shbuf;            // [128 r][256B] full-K swizzled B tile
  __hip_bfloat16* ldsA  = shbuf + 16384;    // per-kt A tile [128 r][128B]
  const int l    = blockIdx.z;
  const int n0   = blockIdx.x * 128;
  const int m0   = blockIdx.y * 128;
  const int tid  = threadIdx.x;
  const int wid  = tid >> 6;
  const int lane = tid & 63;
  const int wr = wid >> 1, wc = wid & 1;
  const int bid = blockIdx.x + 4 * blockIdx.y + 64 * blockIdx.z;   // 0..767

  const f32x4 z = {0.f, 0.f, 0.f, 0.f};
  f32x4* zp = zeroBase + (size_t)bid * 8192;   // 128KB chunk, slot groups 0..31

  // block 0: cos/sin table (consumed by gemm2; stream order guarantees visibility)
  if (bid == 0) {
#pragma unroll
    for (int q = 0; q < 4; ++q) {
      int i = q * 256 + tid;
      int p = i >> 3, f = i & 7;
      double inv = pow(10000.0, -(double)f / 8.0);
      double ang = (double)positions[p] * inv;
      cs[i]        = (float)cos(ang);
      cs[1024 + i] = (float)sin(ang);
    }
  }

  // W2-tail geometry: 4 tiles/block of 64j x 64o
  const int rowg = tid >> 4;          // 0..15
  const int colg = tid & 15;          // o granule (4 f32)
  const int orow = tid >> 3;          // 0..31
  const int jg   = tid & 7;           // j granule (8 bf16)
  const int tbase4 = bid * 4;
  f32x4 rvA0, rvA1, rvA2, rvA3, rvB0, rvB1, rvB2, rvB3;

#define W2_LOAD(P, tt_) do {                                                \
      int t_ = tbase4 + (tt_);                                              \
      int lz_ = t_ >> 8, rem_ = t_ & 255;                                   \
      int j0_ = (rem_ >> 5) * 64, o0_ = (rem_ & 31) * 64;                   \
      const float* ip_ = W2 + (size_t)lz_ * HID * ODIM                      \
                       + (size_t)(j0_ + rowg) * ODIM + o0_ + colg * 4;      \
      P##0 = *(const f32x4*)(ip_);                                          \
      P##1 = *(const f32x4*)(ip_ + (size_t)16 * ODIM);                      \
      P##2 = *(const f32x4*)(ip_ + (size_t)32 * ODIM);                      \
      P##3 = *(const f32x4*)(ip_ + (size_t)48 * ODIM);                      \
    } while (0)

  // B2 staging: W1[l][j][n0+r] -> ldsB2[r][(j4>>1)^(r&7)][j4&1]
  {
    const float* Wp = W1 + (size_t)l * DSUM * HID + n0;
#pragma unroll
    for (int q = 0; q < 16; ++q) {
      int g  = q * 256 + tid;
      int j4 = g >> 7;            // 0..31 (4 consecutive j)
      int r  = g & 127;
      s16x4 w;
#pragma unroll
      for (int jj = 0; jj < 4; ++jj)
        w[jj] = f2bf(Wp[(size_t)(j4 * 4 + jj) * HID + r]);
      int chunk = (j4 >> 1) ^ (r & 7);
      *(s16x4*)((char*)ldsB2 + r * 256 + chunk * 16 + (j4 & 1) * 8) = w;
    }
  }

  // pre-issue W2-tail tiles 0,1: HBM latency hides under K-loop + H epilogue
  W2_LOAD(rvA, 0);
  W2_LOAD(rvB, 1);

  f32x4 acc[4][4];
#pragma unroll
  for (int m = 0; m < 4; ++m)
#pragma unroll
    for (int n = 0; n < 4; ++n)
      acc[m][n] = {0.f, 0.f, 0.f, 0.f};

  const int kq = lane >> 4;

  for (int kt = 0; kt < KTOT / 64; ++kt) {
    LBAR();   // kt=0: orders B2 writes before reads; also guards ldsA reuse
    if (doZero) {
#pragma unroll
      for (int q = 0; q < 4; ++q)
        __builtin_nontemporal_store(z, zp + (kt * 4 + q) * 256 + tid);
    }
    // A: reg-staged f32 -> bf16, swizzled ds_write_b64
#pragma unroll
    for (int j = 0; j < 8; ++j) {
      int s = j * 256 + tid;
      int r = s >> 4, g = s & 15;
      f32x4 v = *(const f32x4*)(summary + (size_t)(m0 + r) * DSUM + kt * 64 + g * 4);
      s16x4 w;
      w[0] = f2bf(v[0]); w[1] = f2bf(v[1]); w[2] = f2bf(v[2]); w[3] = f2bf(v[3]);
      int ch = g >> 1;
      *(s16x4*)((char*)ldsA + r * 128 + ((ch ^ (r & 7)) << 4) + (g & 1) * 8) = w;
    }
    LBAR();
#pragma unroll
    for (int kk = 0; kk < 2; ++kk) {
      short8 af[4], bfr[4];
#pragma unroll
      for (int m = 0; m < 4; ++m) {
        int row = wr * 64 + m * 16 + (lane & 15);
        int off = (kk * 64 + kq * 16) ^ ((row & 7) << 4);
        af[m] = *(const short8*)((const char*)ldsA + row * 128 + off);
      }
#pragma unroll
      for (int n = 0; n < 4; ++n) {
        int row = wc * 64 + n * 16 + (lane & 15);
        int chunk = (kt * 8 + kk * 4 + kq) ^ (row & 7);
        bfr[n] = *(const short8*)((const char*)ldsB2 + row * 256 + chunk * 16);
      }
#pragma unroll
      for (int m = 0; m < 4; ++m)
#pragma unroll
        for (int n = 0; n < 4; ++n)
          acc[m][n] = __builtin_amdgcn_mfma_f32_16x16x32_bf16(af[m], bfr[n], acc[m][n], 0, 0, 0);
    }
  }

  // H epilogue via LDS: [128][136] bf16 padded tile -> 256B-run stores
  LBAR();
#pragma unroll
  for (int n = 0; n < 4; ++n) {
    int col = wc * 64 + n * 16 + (lane & 15);
    float bb = bias[l * NTOT + n0 + col];
#pragma unroll
    for (int m = 0; m < 4; ++m) {
      int rowb = wr * 64 + m * 16 + ((lane >> 4) << 2);
#pragma unroll
      for (int j = 0; j < 4; ++j) {
        float v = acc[m][n][j] + bb;
        v = v > 0.f ? v : 0.f;
        shbuf[(rowb + j) * 136 + col] = __float2bfloat16(v);
      }
    }
  }
  if (doZero) {
#pragma unroll
    for (int i = 0; i < 8; ++i)
      __builtin_nontemporal_store(z, zp + (8 + i) * 256 + tid);
  }
  LBAR();
  {
    __hip_bfloat16* H = Hall + (size_t)l * MROWS * HID;
#pragma unroll
    for (int i = 0; i < 8; ++i) {
      int idx = i * 256 + tid;
      int row = idx >> 4, seg = idx & 15;
      short8 v = *(const short8*)(shbuf + row * 136 + seg * 8);
      *(short8*)(H + (size_t)(m0 + row) * HID + n0 + seg * 8) = v;
    }
  }
  LBAR();   // H LDS reads done before W2 section overwrites shbuf

  // fused W2 -> W2T transpose: 4 x (64j x 64o) tiles, dbuf [64][68] f32 with
  // granule-XOR swizzle, 2-deep reg prefetch, interleaved nt zero-fill.
  {
    float* tb0 = (float*)shbuf;            // 64x68 f32 = 17408B
    float* tb1 = (float*)shbuf + 4352;

#define W2_WRITE(buf, P) do {                                               \
      _Pragma("unroll")                                                     \
      for (int p_ = 0; p_ < 4; ++p_) {                                      \
        int j_ = rowg + 16 * p_;                                            \
        f32x4 vv_ = (p_ == 0) ? P##0 : (p_ == 1) ? P##1 : (p_ == 2) ? P##2 : P##3; \
        *(f32x4*)&(buf)[j_ * 68 + 4 * (colg ^ (j_ >> 3))] = vv_;            \
      }                                                                     \
    } while (0)

#define W2_STORE(buf, tt_) do {                                             \
      int t_ = tbase4 + (tt_);                                              \
      int lz_ = t_ >> 8, rem_ = t_ & 255;                                   \
      int j0_ = (rem_ >> 5) * 64, o0_ = (rem_ & 31) * 64;                   \
      __hip_bfloat16* op_ = W2T + (size_t)lz_ * HID * ODIM;                 \
      _Pragma("unroll")                                                     \
      for (int p_ = 0; p_ < 2; ++p_) {                                      \
        int or_ = orow + 32 * p_;                                           \
        short8 w_;                                                          \
        _Pragma("unroll")                                                   \
        for (int i_ = 0; i_ < 8; ++i_)                                      \
          w_[i_] = f2bf((buf)[(jg * 8 + i_) * 68 + (or_ ^ (4 * jg))]);      \
        *(short8*)(op_ + (size_t)(o0_ + or_) * HID + j0_ + jg * 8) = w_;    \
      }                                                                     \
    } while (0)

#define ZCHUNK(tt_) do { if (doZero) {                                      \
      _Pragma("unroll")                                                     \
      for (int q_ = 0; q_ < 4; ++q_)                                        \
        __builtin_nontemporal_store(z, zp + (16 + (tt_) * 4 + q_) * 256 + tid); \
    } } while (0)

    W2_WRITE(tb0, rvA);
    LBAR();
#pragma unroll 1
    for (int tt = 0; tt < 4; tt += 2) {
      if (tt + 2 < 4) W2_LOAD(rvA, tt + 2);
      W2_STORE(tb0, tt);
      W2_WRITE(tb1, rvB);
      ZCHUNK(tt);
      LBAR();
      if (tt + 3 < 4) W2_LOAD(rvB, tt + 3);
      W2_STORE(tb1, tt + 1);
      if (tt + 2 < 4) W2_WRITE(tb0, rvA);
      ZCHUNK(tt + 1);
      LBAR();
    }
#undef W2_LOAD
#undef W2_WRITE
#undef W2_STORE
#undef ZCHUNK
  }
}

// --- GEMM2 (R17 structure; single change: steady-state vmcnt 6 -> 7 so the
//     counted wait never blocks on the same-iteration zero store — issue
//     order is [store_t, 6 loads(t+2)], and tile t+1's loads are older than
//     store_t, so outstanding<=7 guarantees tile t+1 landed). ---
__global__ __launch_bounds__(256, 2) void gemm2_pipe(
    const __hip_bfloat16* __restrict__ Aall,   // h_bf [12][2048][512]
    const __hip_bfloat16* __restrict__ Ball,   // W2T  [12][2048][512]
    const float* __restrict__ bias,            // b2   [12][2048]
    const float* __restrict__ cs,
    float* __restrict__ O,
    f32x4* __restrict__ zeroBase, int doZero) {
  __shared__ __hip_bfloat16 lds[3 * 12288];    // 3 slots x (A 16KB + B 8KB) = 72 KiB
  const int orig = blockIdx.x + 16 * blockIdx.y + 128 * blockIdx.z;   // x fastest
  const int nw   = (orig & 7) * 192 + (orig >> 3);   // bijective, 1536 % 8 == 0
  const int bx   = nw & 15;
  const int by   = (nw >> 4) & 7;
  const int l    = nw >> 7;
  const int n0  = bx * 128;
  const int m0  = by * 256;
  const int tid = threadIdx.x;
  const int wid = tid >> 6, lane = tid & 63;
  const int wm  = wid >> 1, wn = wid & 1;
  const __hip_bfloat16* A  = Aall + (size_t)l * MROWS * HID;
  const __hip_bfloat16* Bt = Ball + (size_t)l * ODIM * HID;
  f32x4* zq = zeroBase + (size_t)nw * 4096;    // 64KB slice of [0, 96MB)
  const f32x4 zv = {0.f, 0.f, 0.f, 0.f};

  f32x4 acc[8][4];
#pragma unroll
  for (int m = 0; m < 8; ++m)
#pragma unroll
    for (int n = 0; n < 4; ++n)
      acc[m][n] = {0.f, 0.f, 0.f, 0.f};

  int ra[4], ca[4], rb[2], cb[2];
#pragma unroll
  for (int j = 0; j < 4; ++j) {
    int cx = j * 256 + tid;
    ra[j] = cx >> 2; ca[j] = (cx & 3) ^ ((ra[j] >> 1) & 3);
  }
#pragma unroll
  for (int j = 0; j < 2; ++j) {
    int cx = j * 256 + tid;
    rb[j] = cx >> 2; cb[j] = (cx & 3) ^ ((rb[j] >> 1) & 3);
  }

#define STAGE_A(slot, kt) do {                                                      \
    _Pragma("unroll")                                                               \
    for (int j_ = 0; j_ < 4; ++j_)                                                  \
      gload_lds16(A + (size_t)(m0 + ra[j_]) * HID + (kt) * 32 + ca[j_] * 8,         \
                  lds + (slot) * 12288 + j_ * 2048 + wid * 512);                    \
  } while (0)
#define STAGE_B(slot, kt) do {                                                      \
    _Pragma("unroll")                                                               \
    for (int j_ = 0; j_ < 2; ++j_)                                                  \
      gload_lds16(Bt + (size_t)(n0 + rb[j_]) * HID + (kt) * 32 + cb[j_] * 8,        \
                  lds + (slot) * 12288 + 8192 + j_ * 2048 + wid * 512);             \
  } while (0)

  const int kq   = lane >> 4;
  const int rl15 = lane & 15;

#define LD_FRAG(dst, base, rr) do {                                                 \
    int r_ = (rr);                                                                  \
    int off_ = r_ * 64 + ((kq ^ ((r_ >> 1) & 3)) << 4);                             \
    dst = *(const short8*)((const char*)(base) + off_);                             \
  } while (0)

  // prologue: 2 tiles in flight (6 loads/thread per tile)
  STAGE_A(0, 0); STAGE_B(0, 0);
  STAGE_A(1, 1); STAGE_B(1, 1);
  asm volatile("s_waitcnt vmcnt(6)" ::: "memory");   // tile 0 landed
  __builtin_amdgcn_s_barrier();

  const int NT = HID / 32;   // 16
  for (int t = 0; t < NT; ++t) {
    const int cur = t % 3;
    const __hip_bfloat16* sa = lds + cur * 12288;
    const __hip_bfloat16* sb = sa + 8192;
    short8 af[4], bfr[4];

    // zero-fill slice (fire-and-forget; oldest VMEM op this iteration)
    if (doZero)
      __builtin_nontemporal_store(zv, zq + t * 256 + tid);

    // ---- phase 0: m-frags 0..3 ----
#pragma unroll
    for (int n = 0; n < 4; ++n) LD_FRAG(bfr[n], sb, wn * 64 + n * 16 + rl15);
#pragma unroll
    for (int mi = 0; mi < 4; ++mi) LD_FRAG(af[mi], sa, wm * 128 + mi * 16 + rl15);
    if (t + 2 < NT) STAGE_A((t + 2) % 3, t + 2);
    __builtin_amdgcn_s_barrier();
    __builtin_amdgcn_s_setprio(1);
#pragma unroll
    for (int mi = 0; mi < 4; ++mi)
#pragma unroll
      for (int n = 0; n < 4; ++n)
        acc[mi][n] = __builtin_amdgcn_mfma_f32_16x16x32_bf16(af[mi], bfr[n], acc[mi][n], 0, 0, 0);
    __builtin_amdgcn_s_setprio(0);
    __builtin_amdgcn_s_barrier();

    // ---- phase 1: m-frags 4..7 (bfr reused) ----
#pragma unroll
    for (int mi = 0; mi < 4; ++mi) LD_FRAG(af[mi], sa, wm * 128 + 64 + mi * 16 + rl15);
    if (t + 2 < NT) STAGE_B((t + 2) % 3, t + 2);
    __builtin_amdgcn_s_barrier();
    __builtin_amdgcn_s_setprio(1);
#pragma unroll
    for (int mi = 0; mi < 4; ++mi)
#pragma unroll
      for (int n = 0; n < 4; ++n)
        acc[4 + mi][n] = __builtin_amdgcn_mfma_f32_16x16x32_bf16(af[mi], bfr[n], acc[4 + mi][n], 0, 0, 0);
    __builtin_amdgcn_s_setprio(0);
    if (t < NT - 2)       asm volatile("s_waitcnt vmcnt(7)" ::: "memory");
    else if (t == NT - 2) asm volatile("s_waitcnt vmcnt(0)" ::: "memory");
    __builtin_amdgcn_s_barrier();
  }
#undef STAGE_A
#undef STAGE_B
#undef LD_FRAG

  // ---- epilogue: bias + RoPE in-reg, per-wave LDS transpose, nt 1KB stores ----
  __syncthreads();
  const int head = bx;
  const int tkv  = wn;
  const int bidx = by * 2 + wm;
  float* slab = O + ((((size_t)(l + L_ACT) * 2 + tkv) * BDIM + bidx) * NHEAD + head) * (PDIM * DHEAD);
  const bool ropeWave = (tkv == 0);

  float bb[4];
#pragma unroll
  for (int n = 0; n < 4; ++n) bb[n] = bias[l * ODIM + n0 + wn * 64 + n * 16 + rl15];

  float* Tw = (float*)lds + wid * 2080;   // 32 x 65 f32 per wave

#pragma unroll
  for (int c = 0; c < 4; ++c) {           // p-chunk [c*32, c*32+32)
#pragma unroll
    for (int mh = 0; mh < 2; ++mh) {
      int mf = c * 2 + mh;
      int pl = mh * 16 + (lane >> 4) * 4;
#pragma unroll
      for (int n = 0; n < 4; ++n) {
#pragma unroll
        for (int j = 0; j < 4; ++j) {
          float v = acc[mf][n][j] + bb[n];
          if (ropeWave && n == 0) {
            float partner = __shfl_xor(v, 8);
            int p = c * 32 + pl + j;
            float cv = cs[p * 8 + (lane & 7)];
            float sv = cs[1024 + p * 8 + (lane & 7)];
            v = v * cv + (((lane & 15) < 8) ? -partner : partner) * sv;
          }
          Tw[(pl + j) * 65 + n * 16 + rl15] = v;
        }
      }
    }
#pragma unroll
    for (int it = 0; it < 8; ++it) {
      int pl = it * 4 + (lane >> 4);
      f32x4 vv = *(const f32x4*)(Tw + pl * 65 + rl15 * 4);
      __builtin_nontemporal_store(vv, (f32x4*)(slab + (size_t)(c * 32 + pl) * DHEAD + rl15 * 4));
    }
  }
}

extern "C" void kernel_launch(void* const* d_in, const int* in_sizes, int n_in,
                              void* d_out, int out_size, void* d_ws, size_t ws_size,
                              hipStream_t stream) {
  const float* summary   = (const float*)d_in[0];
  const int*   positions = (const int*)d_in[1];
  const float* W1 = (const float*)d_in[2];
  const float* b1 = (const float*)d_in[3];
  const float* W2 = (const float*)d_in[4];
  const float* b2 = (const float*)d_in[5];
  float* out = (float*)d_out;

  // Scratch: h_bf 25165824 | W2T 25165824 | cs 8192
  const size_t SCRATCH_BYTES = 25165824ULL + 25165824ULL + 8192ULL;
  const bool useWs = (ws_size >= SCRATCH_BYTES);
  char* sc = useWs ? (char*)d_ws : (char*)d_out;
  __hip_bfloat16* h_bf = (__hip_bfloat16*)sc;
  __hip_bfloat16* W2T  = (__hip_bfloat16*)(sc + 25165824);
  float*          cs   = (float*)(sc + 50331648);

  // zero region split: gemm2 covers [0, 100663296), gemm1 covers the rest.
  gemm1_128<<<dim3(HID / 128, MROWS / 128, L_ACT), 256, 0, stream>>>(
      summary, W1, positions, b1, h_bf, W2, W2T, cs,
      (f32x4*)((char*)d_out + 100663296), useWs ? 1 : 0);
  gemm2_pipe<<<dim3(ODIM / 128, MROWS / 256, L_ACT), 256, 0, stream>>>(
      h_bf, W2T, b2, cs, out, (f32x4*)d_out, useWs ? 1 : 0);

  if (!useWs)   // scratch aliased d_out: zero AFTER gemm2 has consumed it
    zerofill_kernel<<<2048, 256, 0, stream>>>((f32x4*)d_out, 12582912);
}